// Round 3
// baseline (916.209 us; speedup 1.0000x reference)
//
#include <hip/hip_runtime.h>
#include <math.h>

#define BATCH 32768
#define DD 256
#define KC 100
#define NATOMS 262144

typedef unsigned short u16;
typedef __attribute__((ext_vector_type(8))) short bf16x8;
typedef __attribute__((ext_vector_type(4))) float f32x4;

union Pack8 { uint4 v; u16 us[8]; };

__device__ inline u16 f2b(float f) {
    unsigned u = __float_as_uint(f);
    unsigned r = (u + 0x7fffu + ((u >> 16) & 1u)) >> 16;
    return (u16)r;
}
__device__ inline float b2f(u16 x) { return __uint_as_float(((unsigned)x) << 16); }

// ---------------- ws layout (float offsets) ----------------
// acc[16] @0, colsum[768] @16, colsum2[768] @784, bnscale[768] @1552,
// bnshift[768] @2320, enorm[128] @3088, gsums[32768] @3216, gcnts[32768] @35984,
// idx int[32768] @68752,
// wt_proj1 @101632, wt_proj2 @134400, wt_invp1 @167168, wt_invp2 @199936 (each 32768 fl of bf16)
// wat @232704 (14336 fl), emb_b @247040 (12800 fl),
// z1b @259840, h_b @4454144, p1_b @8648448 (each 4194304 fl of bf16)  -> ~49 MB total

template<int NT>
__device__ inline void block_reduce_add(float v, float* target) {
    __shared__ float red[NT];
    red[threadIdx.x] = v;
    __syncthreads();
    for (int s = NT/2; s > 0; s >>= 1) {
        if ((int)threadIdx.x < s) red[threadIdx.x] += red[threadIdx.x + s];
        __syncthreads();
    }
    if (threadIdx.x == 0) atomicAdd(target, red[0]);
}

// ---------------- setup conversions ----------------
__global__ __launch_bounds__(256) void transpose_cvt256_k(const float* __restrict__ W,
                                                          u16* __restrict__ Wt) {
    int o = blockIdx.x * 256 + threadIdx.x;       // 65536
    int n = o >> 8, k = o & 255;
    Wt[o] = f2b(W[k * 256 + n]);
}
__global__ __launch_bounds__(256) void transpose_cvt_atom_k(const float* __restrict__ W,
                                                            u16* __restrict__ Wt) {
    int o = blockIdx.x * 256 + threadIdx.x;       // 112*256
    int n = o >> 8, k = o & 255;
    Wt[o] = (n < KC) ? f2b(W[k * KC + n]) : (u16)0;
}
__global__ __launch_bounds__(256) void cvt_bf16_k(const float* __restrict__ x,
                                                  u16* __restrict__ y, int n8) {
    int i = blockIdx.x * 256 + threadIdx.x;
    if (i < n8) {
        const float4* p = (const float4*)(x + (size_t)i * 8);
        float4 f0 = p[0], f1 = p[1];
        Pack8 pk;
        pk.us[0]=f2b(f0.x); pk.us[1]=f2b(f0.y); pk.us[2]=f2b(f0.z); pk.us[3]=f2b(f0.w);
        pk.us[4]=f2b(f1.x); pk.us[5]=f2b(f1.y); pk.us[6]=f2b(f1.z); pk.us[7]=f2b(f1.w);
        *(uint4*)(y + (size_t)i * 8) = pk.v;
    }
}

// ---------------- VQ (fp32) ----------------
__global__ __launch_bounds__(128) void vq_enorm_k(const float* __restrict__ emb,
                                                  float* __restrict__ enorm) {
    int k = threadIdx.x;
    if (k < KC) {
        float s = 0.f;
        for (int d = 0; d < DD; ++d) { float e = emb[k*DD + d]; s = fmaf(e, e, s); }
        enorm[k] = 0.5f * s;
    }
}

__global__ __launch_bounds__(256) void vq_argmin_k(const float* __restrict__ z2,
                                                   const float* __restrict__ emb,
                                                   const float* __restrict__ enorm,
                                                   int* __restrict__ idx) {
    int b = blockIdx.x * 256 + threadIdx.x;
    const float* zr = z2 + (size_t)b * DD;
    float best = 3.4e38f; int bi = 0;
    for (int kc = 0; kc < KC; kc += 25) {
        float a[25];
        #pragma unroll
        for (int j = 0; j < 25; ++j) a[j] = enorm[kc + j];
        for (int d = 0; d < DD; ++d) {
            float z = zr[d];
            #pragma unroll
            for (int j = 0; j < 25; ++j)
                a[j] = fmaf(-z, emb[(kc + j)*DD + d], a[j]);
        }
        #pragma unroll
        for (int j = 0; j < 25; ++j)
            if (a[j] < best) { best = a[j]; bi = kc + j; }
    }
    idx[b] = bi;
}

__global__ __launch_bounds__(256) void vq_loss_k(const float* __restrict__ z2,
                                                 const float* __restrict__ emb,
                                                 const int* __restrict__ idx,
                                                 float* acc) {
    size_t stride = (size_t)gridDim.x * 256;
    float s = 0.f;
    for (size_t e = (size_t)blockIdx.x * 256 + threadIdx.x; e < (size_t)BATCH * DD; e += stride) {
        int b = (int)(e >> 8);
        int d = (int)(e & 255);
        float q = emb[idx[b]*DD + d];
        float dd = q - z2[e];
        s = fmaf(dd, dd, s);
    }
    block_reduce_add<256>(s, acc + 0);
}

// ---------------- MFMA MLP GEMM: 64 rows x 256 cols per block, 8 waves ----------------
// MODE_A: 0=direct bf16 A, 1=bf16 h with BN(scale,shift)+ReLU, 2=gather emb_b[gidx[r]]
// MODE_T: 1=f32 T direct, 2=f32 emb gather
template<int MODE_A, int MODE_T, int WRITE_C, int DO_STATS, int DO_LOSS>
__global__ __launch_bounds__(512) void mlp_gemm(
    const u16* __restrict__ Ab, const u16* __restrict__ Wt,
    const float* __restrict__ bias,
    const float* __restrict__ bnscale, const float* __restrict__ bnshift,
    const int* __restrict__ gidx, const float* __restrict__ embf,
    u16* __restrict__ Cb,
    float* __restrict__ colsum, float* __restrict__ colsum2,
    const float* __restrict__ Tf, float* __restrict__ loss_acc)
{
    __shared__ u16 As[64 * 32];
    __shared__ u16 Bs[256 * 32];
    const int t = threadIdx.x;
    const int row0 = blockIdx.x * 64;
    const int lane = t & 63, wave = t >> 6;
    const int wr = wave >> 2, wc = wave & 3;       // 2 x 4 wave grid
    const int l15 = lane & 15, lg = lane >> 4;
    const int am = t >> 2, akc = t & 3;            // A stage: threads 0..255

    f32x4 acc[2][4];
    #pragma unroll
    for (int mt = 0; mt < 2; ++mt)
        #pragma unroll
        for (int j = 0; j < 4; ++j)
            acc[mt][j] = (f32x4){0.f, 0.f, 0.f, 0.f};

    for (int k0 = 0; k0 < DD; k0 += 32) {
        if (t < 256) {
            uint4 d;
            if (MODE_A == 2) {
                int code = gidx[row0 + am];
                d = *(const uint4*)(Ab + (size_t)code * DD + k0 + akc * 8);
            } else {
                d = *(const uint4*)(Ab + (size_t)(row0 + am) * DD + k0 + akc * 8);
            }
            if (MODE_A == 1) {
                Pack8 pk; pk.v = d;
                #pragma unroll
                for (int e = 0; e < 8; ++e) {
                    int k = k0 + akc * 8 + e;
                    float v = fmaf(b2f(pk.us[e]), bnscale[k], bnshift[k]);
                    pk.us[e] = f2b(v > 0.f ? v : 0.f);
                }
                d = pk.v;
            }
            *(uint4*)(As + (((am * 32 + akc * 8) ^ ((am & 7) << 3)))) = d;
        }
        #pragma unroll
        for (int q = 0; q < 2; ++q) {
            int ch = t * 2 + q;                    // 0..1023
            int bn = ch >> 2, bkc = ch & 3;
            uint4 d = *(const uint4*)(Wt + bn * DD + k0 + bkc * 8);
            *(uint4*)(Bs + (((bn * 32 + bkc * 8) ^ ((bn & 7) << 3)))) = d;
        }
        __syncthreads();

        bf16x8 af[2], bfr[4];
        #pragma unroll
        for (int mt = 0; mt < 2; ++mt) {
            int m = wr * 32 + mt * 16 + l15;
            af[mt] = *(const bf16x8*)(As + (((m * 32 + lg * 8) ^ ((m & 7) << 3))));
        }
        #pragma unroll
        for (int j = 0; j < 4; ++j) {
            int n = wc * 64 + j * 16 + l15;
            bfr[j] = *(const bf16x8*)(Bs + (((n * 32 + lg * 8) ^ ((n & 7) << 3))));
        }
        #pragma unroll
        for (int mt = 0; mt < 2; ++mt)
            #pragma unroll
            for (int j = 0; j < 4; ++j)
                acc[mt][j] = __builtin_amdgcn_mfma_f32_16x16x32_bf16(af[mt], bfr[j], acc[mt][j], 0, 0, 0);
        __syncthreads();
    }

    // epilogue: D layout col=lane&15, row=4*(lane>>4)+reg
    float lsum = 0.f;
    #pragma unroll
    for (int j = 0; j < 4; ++j) {
        int c = wc * 64 + j * 16 + l15;
        float bc = bias[c];
        float cs = 0.f, cs2 = 0.f;
        #pragma unroll
        for (int mt = 0; mt < 2; ++mt) {
            #pragma unroll
            for (int r = 0; r < 4; ++r) {
                int row = row0 + wr * 32 + mt * 16 + lg * 4 + r;
                float y = acc[mt][j][r] + bc;
                if (WRITE_C) Cb[(size_t)row * DD + c] = f2b(y);
                if (DO_STATS) { cs += y; cs2 = fmaf(y, y, cs2); }
                if (DO_LOSS) {
                    float tv = (MODE_T == 2) ? embf[(size_t)gidx[row] * DD + c]
                                             : Tf[(size_t)row * DD + c];
                    float dd = y - tv;
                    lsum = fmaf(dd, dd, lsum);
                }
            }
        }
        if (DO_STATS) {
            cs  += __shfl_xor(cs, 16);  cs  += __shfl_xor(cs, 32);
            cs2 += __shfl_xor(cs2, 16); cs2 += __shfl_xor(cs2, 32);
            if (lg == 0) {
                atomicAdd(&colsum[c], cs);
                atomicAdd(&colsum2[c], cs2);
            }
        }
    }
    if (DO_LOSS) block_reduce_add<512>(lsum, loss_acc);
}

__global__ __launch_bounds__(256) void bn_finalize_k(
    const float* __restrict__ cs, const float* __restrict__ cs2,
    const float* __restrict__ g, const float* __restrict__ beta,
    float* __restrict__ scale, float* __restrict__ shift)
{
    int c = threadIdx.x;
    float mu  = cs[c]  * (1.f / (float)BATCH);
    float var = cs2[c] * (1.f / (float)BATCH) - mu * mu;
    float sc = g[c] * rsqrtf(var + 1e-5f);
    scale[c] = sc;
    shift[c] = beta[c] - mu * sc;
}

// ---------------- lattice ----------------
__global__ __launch_bounds__(256) void latt_k(
    const float* __restrict__ emb, const int* __restrict__ idx,
    const float* __restrict__ lattW, const float* __restrict__ lattb,
    const float* __restrict__ smean, const float* __restrict__ sstd,
    const float* __restrict__ lsc, float* acc)
{
    int b = blockIdx.x * 256 + threadIdx.x;
    const float* q = emb + (size_t)idx[b] * DD;
    float a[6] = {0.f,0.f,0.f,0.f,0.f,0.f};
    for (int d = 0; d < DD; ++d) {
        float qv = q[d];
        #pragma unroll
        for (int j = 0; j < 6; ++j) a[j] = fmaf(qv, lattW[d*6 + j], a[j]);
    }
    float s = 0.f;
    #pragma unroll
    for (int j = 0; j < 6; ++j) {
        float pred = a[j] + lattb[j];
        float tgt = (lsc[(size_t)b*6 + j] - smean[j]) / sstd[j];
        float dd = pred - tgt;
        s = fmaf(dd, dd, s);
    }
    block_reduce_add<256>(s, acc + 4);
}

// ---------------- atom: MFMA GEMM 64 rows x 112 cols + in-register CE ----------------
__global__ __launch_bounds__(256) void atom_k(
    const float* __restrict__ zn, const u16* __restrict__ Wat, const float* __restrict__ ba,
    const int* __restrict__ atomic_nums, const int* __restrict__ batch_idx,
    float* __restrict__ gsums, float* __restrict__ gcnts)
{
    __shared__ u16 As[64 * 32];
    __shared__ u16 Bs[112 * 32];
    const int t = threadIdx.x;
    const int n0 = blockIdx.x * 64;
    const int lane = t & 63, wave = t >> 6;
    const int l15 = lane & 15, lg = lane >> 4;
    const int am = t >> 2, akc = t & 3;

    f32x4 acc[7];
    #pragma unroll
    for (int j = 0; j < 7; ++j) acc[j] = (f32x4){0.f, 0.f, 0.f, 0.f};

    for (int k0 = 0; k0 < DD; k0 += 32) {
        {   // A stage: 256 chunks, f32 -> bf16
            const float* src = zn + (size_t)(n0 + am) * DD + k0 + akc * 8;
            float4 f0 = *(const float4*)src;
            float4 f1 = *(const float4*)(src + 4);
            Pack8 pk;
            pk.us[0]=f2b(f0.x); pk.us[1]=f2b(f0.y); pk.us[2]=f2b(f0.z); pk.us[3]=f2b(f0.w);
            pk.us[4]=f2b(f1.x); pk.us[5]=f2b(f1.y); pk.us[6]=f2b(f1.z); pk.us[7]=f2b(f1.w);
            *(uint4*)(As + (((am * 32 + akc * 8) ^ ((am & 7) << 3)))) = pk.v;
        }
        {   // B stage: 448 chunks
            int bn = t >> 2, bkc = t & 3;
            uint4 d = *(const uint4*)(Wat + bn * DD + k0 + bkc * 8);
            *(uint4*)(Bs + (((bn * 32 + bkc * 8) ^ ((bn & 7) << 3)))) = d;
            int ch = t + 256;
            if (ch < 448) {
                int bn2 = ch >> 2, bkc2 = ch & 3;
                uint4 d2 = *(const uint4*)(Wat + bn2 * DD + k0 + bkc2 * 8);
                *(uint4*)(Bs + (((bn2 * 32 + bkc2 * 8) ^ ((bn2 & 7) << 3)))) = d2;
            }
        }
        __syncthreads();

        int m = wave * 16 + l15;
        bf16x8 af = *(const bf16x8*)(As + (((m * 32 + lg * 8) ^ ((m & 7) << 3))));
        #pragma unroll
        for (int j = 0; j < 7; ++j) {
            int n = j * 16 + l15;
            bf16x8 bfv = *(const bf16x8*)(Bs + (((n * 32 + lg * 8) ^ ((n & 7) << 3))));
            acc[j] = __builtin_amdgcn_mfma_f32_16x16x32_bf16(af, bfv, acc[j], 0, 0, 0);
        }
        __syncthreads();
    }

    // CE per output row; row = wave*16 + lg*4 + r, col = j*16 + l15
    #pragma unroll
    for (int r = 0; r < 4; ++r) {
        float y[7];
        float mx = -3.4e38f;
        #pragma unroll
        for (int j = 0; j < 7; ++j) {
            int c = j * 16 + l15;
            y[j] = (c < KC) ? (acc[j][r] + ba[c]) : -3.4e38f;
            mx = fmaxf(mx, y[j]);
        }
        mx = fmaxf(mx, __shfl_xor(mx, 1));
        mx = fmaxf(mx, __shfl_xor(mx, 2));
        mx = fmaxf(mx, __shfl_xor(mx, 4));
        mx = fmaxf(mx, __shfl_xor(mx, 8));
        float s = 0.f;
        #pragma unroll
        for (int j = 0; j < 7; ++j) {
            int c = j * 16 + l15;
            if (c < KC) s += expf(y[j] - mx);
        }
        s += __shfl_xor(s, 1); s += __shfl_xor(s, 2);
        s += __shfl_xor(s, 4); s += __shfl_xor(s, 8);
        int n = n0 + wave * 16 + lg * 4 + r;
        int tgt = atomic_nums[n];
        float tv = 0.f;
        #pragma unroll
        for (int j = 0; j < 7; ++j)
            tv += (((tgt & 15) == l15) && ((tgt >> 4) == j)) ? y[j] : 0.f;
        tv += __shfl_xor(tv, 1); tv += __shfl_xor(tv, 2);
        tv += __shfl_xor(tv, 4); tv += __shfl_xor(tv, 8);
        if (l15 == 0) {
            float ce = logf(s) + mx - tv;
            int b = batch_idx[n];
            atomicAdd(&gsums[b], ce);
            atomicAdd(&gcnts[b], 1.f);
        }
    }
}

__global__ __launch_bounds__(256) void atom_final_k(const float* __restrict__ gsums,
                                                    const float* __restrict__ gcnts,
                                                    float* acc) {
    int b = blockIdx.x * 256 + threadIdx.x;
    float v = gsums[b] / fmaxf(gcnts[b], 1.f);
    block_reduce_add<256>(v, acc + 5);
}

__global__ void finalize_k(const float* __restrict__ acc, float* __restrict__ out) {
    if (threadIdx.x == 0) {
        const float inv_bd = 1.f / ((float)BATCH * (float)DD);
        float cyc = (acc[1] + acc[2] + acc[3]) * inv_bd;
        float vq = 2.f * acc[0] * inv_bd;
        float latt = acc[4] / ((float)BATCH * 6.f) * 10.f;
        float atom = acc[5] * (1.f / (float)BATCH);
        out[0] = cyc + atom + latt + vq;
        out[1] = cyc;
        out[2] = atom;
        out[3] = latt;
        out[4] = vq;
    }
}

extern "C" void kernel_launch(void* const* d_in, const int* in_sizes, int n_in,
                              void* d_out, int out_size, void* d_ws, size_t ws_size,
                              hipStream_t stream)
{
    const float* z1      = (const float*)d_in[0];
    const float* z2      = (const float*)d_in[1];
    const float* zn      = (const float*)d_in[2];
    const float* emb     = (const float*)d_in[3];
    const float* proj_W1 = (const float*)d_in[4];
    const float* proj_b1 = (const float*)d_in[5];
    const float* proj_g  = (const float*)d_in[6];
    const float* proj_be = (const float*)d_in[7];
    const float* proj_W2 = (const float*)d_in[8];
    const float* proj_b2 = (const float*)d_in[9];
    const float* invp_W1 = (const float*)d_in[10];
    const float* invp_b1 = (const float*)d_in[11];
    const float* invp_g  = (const float*)d_in[12];
    const float* invp_be = (const float*)d_in[13];
    const float* invp_W2 = (const float*)d_in[14];
    const float* invp_b2 = (const float*)d_in[15];
    const float* latt_W  = (const float*)d_in[16];
    const float* latt_b  = (const float*)d_in[17];
    const float* atom_W  = (const float*)d_in[18];
    const float* atom_b  = (const float*)d_in[19];
    const float* smean   = (const float*)d_in[20];
    const float* sstd    = (const float*)d_in[21];
    const float* lsc     = (const float*)d_in[22];
    const int* batch_idx   = (const int*)d_in[24];
    const int* atomic_nums = (const int*)d_in[25];
    float* out = (float*)d_out;
    float* ws  = (float*)d_ws;

    float* acc     = ws + 0;
    float* colsum  = ws + 16;
    float* colsum2 = ws + 784;
    float* bnscale = ws + 1552;
    float* bnshift = ws + 2320;
    float* enorm   = ws + 3088;
    float* gsums   = ws + 3216;
    float* gcnts   = ws + 35984;
    int*   idx     = (int*)(ws + 68752);
    u16* wt_proj1  = (u16*)(ws + 101632);
    u16* wt_proj2  = (u16*)(ws + 134400);
    u16* wt_invp1  = (u16*)(ws + 167168);
    u16* wt_invp2  = (u16*)(ws + 199936);
    u16* wat       = (u16*)(ws + 232704);
    u16* emb_b     = (u16*)(ws + 247040);
    u16* z1b       = (u16*)(ws + 259840);
    u16* h_b       = (u16*)(ws + 4454144);
    u16* p1_b      = (u16*)(ws + 8648448);

    hipMemsetAsync(d_ws, 0, 68752 * sizeof(float), stream);

    // setup conversions
    transpose_cvt256_k<<<256, 256, 0, stream>>>(proj_W1, wt_proj1);
    transpose_cvt256_k<<<256, 256, 0, stream>>>(proj_W2, wt_proj2);
    transpose_cvt256_k<<<256, 256, 0, stream>>>(invp_W1, wt_invp1);
    transpose_cvt256_k<<<256, 256, 0, stream>>>(invp_W2, wt_invp2);
    transpose_cvt_atom_k<<<112, 256, 0, stream>>>(atom_W, wat);
    cvt_bf16_k<<<13, 256, 0, stream>>>(emb, emb_b, KC * DD / 8);
    cvt_bf16_k<<<4096, 256, 0, stream>>>(z1, z1b, BATCH * DD / 8);

    // VQ
    vq_enorm_k<<<1, 128, 0, stream>>>(emb, enorm);
    vq_argmin_k<<<BATCH/256, 256, 0, stream>>>(z2, emb, enorm, idx);
    vq_loss_k<<<1024, 256, 0, stream>>>(z2, emb, idx, acc);

    // MLP1: p1 = mlp_bn(z1, proj), loss_p vs quant (emb gather)
    mlp_gemm<0,1,1,1,0><<<512, 512, 0, stream>>>(z1b, wt_proj1, proj_b1, nullptr, nullptr,
        idx, emb, h_b, colsum+0, colsum2+0, nullptr, nullptr);
    bn_finalize_k<<<1, 256, 0, stream>>>(colsum+0, colsum2+0, proj_g, proj_be, bnscale+0, bnshift+0);
    mlp_gemm<1,2,1,0,1><<<512, 512, 0, stream>>>(h_b, wt_proj2, proj_b2, bnscale+0, bnshift+0,
        idx, emb, p1_b, nullptr, nullptr, nullptr, acc+1);
    // MLP2: mlp_bn(quant, invp), loss_i vs z1
    mlp_gemm<2,1,1,1,0><<<512, 512, 0, stream>>>(emb_b, wt_invp1, invp_b1, nullptr, nullptr,
        idx, emb, h_b, colsum+256, colsum2+256, nullptr, nullptr);
    bn_finalize_k<<<1, 256, 0, stream>>>(colsum+256, colsum2+256, invp_g, invp_be, bnscale+256, bnshift+256);
    mlp_gemm<1,1,0,0,1><<<512, 512, 0, stream>>>(h_b, wt_invp2, invp_b2, bnscale+256, bnshift+256,
        idx, emb, nullptr, nullptr, nullptr, z1, acc+2);
    // MLP3: mlp_bn(p1, invp), loss_c vs z1
    mlp_gemm<0,1,1,1,0><<<512, 512, 0, stream>>>(p1_b, wt_invp1, invp_b1, nullptr, nullptr,
        idx, emb, h_b, colsum+512, colsum2+512, nullptr, nullptr);
    bn_finalize_k<<<1, 256, 0, stream>>>(colsum+512, colsum2+512, invp_g, invp_be, bnscale+512, bnshift+512);
    mlp_gemm<1,1,0,0,1><<<512, 512, 0, stream>>>(h_b, wt_invp2, invp_b2, bnscale+512, bnshift+512,
        idx, emb, nullptr, nullptr, nullptr, z1, acc+3);

    latt_k<<<BATCH/256, 256, 0, stream>>>(emb, idx, latt_W, latt_b, smean, sstd, lsc, acc);
    atom_k<<<NATOMS/64, 256, 0, stream>>>(zn, wat, atom_b, atomic_nums, batch_idx, gsums, gcnts);
    atom_final_k<<<BATCH/256, 256, 0, stream>>>(gsums, gcnts, acc);
    finalize_k<<<1, 64, 0, stream>>>(acc, out);
}

// Round 5
// 731.573 us; speedup vs baseline: 1.2524x; 1.2524x over previous
//
#include <hip/hip_runtime.h>
#include <math.h>

#define BATCH 32768
#define DD 256
#define KC 100
#define NATOMS 262144

typedef unsigned short u16;
typedef __attribute__((ext_vector_type(8))) short bf16x8;
typedef __attribute__((ext_vector_type(4))) float f32x4;

union Pack8 { uint4 v; u16 us[8]; };

__device__ inline u16 f2b(float f) {
    unsigned u = __float_as_uint(f);
    unsigned r = (u + 0x7fffu + ((u >> 16) & 1u)) >> 16;
    return (u16)r;
}
__device__ inline float b2f(u16 x) { return __uint_as_float(((unsigned)x) << 16); }

// ---------------- ws layout (float offsets) ----------------
// acc[16]@0 colsum[768]@16 colsum2[768]@784 gsums[32768]@1552 gcnts[32768]@34320
//   (zero first 67088 floats)
// enorm[128]@67088 idx int[32768]@67216
// wt_proj1@100000 wt_proj2@132768 wt_invp1@165536 wt_invp2@198304 (32768 fl each)
// wat@231072 (14336 fl) embT_hi@245408 embT_lo@259744 (14336 fl each)
// emb_b@274080 (12800 fl) h_b@286880 p1_b@4481184 (4194304 fl each) -> ~34.7MB

template<int NT>
__device__ inline void block_reduce_add(float v, float* target) {
    __shared__ float red[NT];
    red[threadIdx.x] = v;
    __syncthreads();
    for (int s = NT/2; s > 0; s >>= 1) {
        if ((int)threadIdx.x < s) red[threadIdx.x] += red[threadIdx.x + s];
        __syncthreads();
    }
    if (threadIdx.x == 0) atomicAdd(target, red[0]);
}

// ---------------- setup conversions ----------------
__global__ __launch_bounds__(256) void transpose_cvt256_k(const float* __restrict__ W,
                                                          u16* __restrict__ Wt) {
    int o = blockIdx.x * 256 + threadIdx.x;       // 65536, Wt[n*256+k] = W[k*256+n]
    int n = o >> 8, k = o & 255;
    Wt[o] = f2b(W[k * 256 + n]);
}
__global__ __launch_bounds__(256) void transpose_cvt_atom_k(const float* __restrict__ W,
                                                            u16* __restrict__ Wt) {
    int o = blockIdx.x * 256 + threadIdx.x;       // 112*256
    int n = o >> 8, k = o & 255;
    Wt[o] = (n < KC) ? f2b(W[k * KC + n]) : (u16)0;
}
__global__ __launch_bounds__(256) void embT_k(const float* __restrict__ emb,
                                              u16* __restrict__ hi, u16* __restrict__ lo) {
    int o = blockIdx.x * 256 + threadIdx.x;       // 112*256; [code][d]
    int n = o >> 8, d = o & 255;
    float v = (n < KC) ? emb[n * DD + d] : 0.f;
    u16 h = f2b(v);
    hi[o] = h;
    lo[o] = f2b(v - b2f(h));
}
__global__ __launch_bounds__(256) void cvt_bf16_k(const float* __restrict__ x,
                                                  u16* __restrict__ y, int n8) {
    int i = blockIdx.x * 256 + threadIdx.x;
    if (i < n8) {
        const float4* p = (const float4*)(x + (size_t)i * 8);
        float4 f0 = p[0], f1 = p[1];
        Pack8 pk;
        pk.us[0]=f2b(f0.x); pk.us[1]=f2b(f0.y); pk.us[2]=f2b(f0.z); pk.us[3]=f2b(f0.w);
        pk.us[4]=f2b(f1.x); pk.us[5]=f2b(f1.y); pk.us[6]=f2b(f1.z); pk.us[7]=f2b(f1.w);
        *(uint4*)(y + (size_t)i * 8) = pk.v;
    }
}
__global__ __launch_bounds__(64) void enorm_k(const float* __restrict__ emb,
                                              float* __restrict__ enorm) {
    int k = blockIdx.x, lane = threadIdx.x;
    float4 v = *(const float4*)(emb + (size_t)k * DD + lane * 4);
    float s = v.x*v.x + v.y*v.y + v.z*v.z + v.w*v.w;
    #pragma unroll
    for (int off = 1; off < 64; off <<= 1) s += __shfl_xor(s, off);
    if (lane == 0) enorm[k] = 0.5f * s;
}

// ---------------- VQ: MFMA hi/lo distance + fused argmin + vq_loss ----------------
__global__ __launch_bounds__(256) void vq_k(
    const float* __restrict__ z2, const u16* __restrict__ Eh, const u16* __restrict__ El,
    const float* __restrict__ enorm, int* __restrict__ idx, float* acc)
{
    __shared__ u16 Ah[64*32], Al[64*32], Bh[112*32], Bl[112*32];
    const int t = threadIdx.x;
    const int n0 = blockIdx.x * 64;
    const int lane = t & 63, wave = t >> 6;
    const int l15 = lane & 15, lg = lane >> 4;
    const int am = t >> 2, akc = t & 3;

    f32x4 dot[7];
    #pragma unroll
    for (int j = 0; j < 7; ++j) dot[j] = (f32x4){0.f, 0.f, 0.f, 0.f};

    for (int k0 = 0; k0 < DD; k0 += 32) {
        {   // A stage: f32 -> hi/lo bf16
            const float* src = z2 + (size_t)(n0 + am) * DD + k0 + akc * 8;
            float4 f0 = *(const float4*)src;
            float4 f1 = *(const float4*)(src + 4);
            float fv[8] = {f0.x, f0.y, f0.z, f0.w, f1.x, f1.y, f1.z, f1.w};
            Pack8 ph, pl;
            #pragma unroll
            for (int e = 0; e < 8; ++e) {
                u16 h = f2b(fv[e]);
                ph.us[e] = h;
                pl.us[e] = f2b(fv[e] - b2f(h));
            }
            int off = (am * 32 + akc * 8) ^ ((am & 7) << 3);
            *(uint4*)(Ah + off) = ph.v;
            *(uint4*)(Al + off) = pl.v;
        }
        {   // B stage: 448 chunks each for hi/lo
            int bn = t >> 2, bkc = t & 3;
            int off = (bn * 32 + bkc * 8) ^ ((bn & 7) << 3);
            *(uint4*)(Bh + off) = *(const uint4*)(Eh + bn * DD + k0 + bkc * 8);
            *(uint4*)(Bl + off) = *(const uint4*)(El + bn * DD + k0 + bkc * 8);
            int c2 = t + 256;
            if (c2 < 448) {
                int bn2 = c2 >> 2, bkc2 = c2 & 3;
                int off2 = (bn2 * 32 + bkc2 * 8) ^ ((bn2 & 7) << 3);
                *(uint4*)(Bh + off2) = *(const uint4*)(Eh + bn2 * DD + k0 + bkc2 * 8);
                *(uint4*)(Bl + off2) = *(const uint4*)(El + bn2 * DD + k0 + bkc2 * 8);
            }
        }
        __syncthreads();

        int m = wave * 16 + l15;
        int aoff = (m * 32 + lg * 8) ^ ((m & 7) << 3);
        bf16x8 ah = *(const bf16x8*)(Ah + aoff);
        bf16x8 al = *(const bf16x8*)(Al + aoff);
        #pragma unroll
        for (int j = 0; j < 7; ++j) {
            int n = j * 16 + l15;
            int boff = (n * 32 + lg * 8) ^ ((n & 7) << 3);
            bf16x8 bh = *(const bf16x8*)(Bh + boff);
            bf16x8 bl = *(const bf16x8*)(Bl + boff);
            dot[j] = __builtin_amdgcn_mfma_f32_16x16x32_bf16(ah, bh, dot[j], 0, 0, 0);
            dot[j] = __builtin_amdgcn_mfma_f32_16x16x32_bf16(ah, bl, dot[j], 0, 0, 0);
            dot[j] = __builtin_amdgcn_mfma_f32_16x16x32_bf16(al, bh, dot[j], 0, 0, 0);
        }
        __syncthreads();
    }

    // epilogue: argmin + vq accumulation. row = n0 + wave*16 + lg*4 + r, col = j*16+l15
    float vq_local = 0.f;
    #pragma unroll
    for (int r = 0; r < 4; ++r) {
        int row = n0 + wave * 16 + lg * 4 + r;
        float bv = 3.4e38f; int bc = 1000;
        #pragma unroll
        for (int j = 0; j < 7; ++j) {
            int c = j * 16 + l15;
            if (c < KC) {
                float y = enorm[c] - dot[j][r];      // 0.5||e||^2 - z.e
                if (y < bv) { bv = y; bc = c; }
            }
        }
        #pragma unroll
        for (int off = 1; off < 16; off <<= 1) {
            float ov = __shfl_xor(bv, off);
            int   oc = __shfl_xor(bc, off);
            if (ov < bv || (ov == bv && oc < bc)) { bv = ov; bc = oc; }
        }
        // ||z||^2 for this row (16 lanes x 16 f32)
        float zs = 0.f;
        const float* zr = z2 + (size_t)row * DD + l15 * 16;
        #pragma unroll
        for (int u = 0; u < 4; ++u) {
            float4 v = *(const float4*)(zr + u * 4);
            zs = fmaf(v.x, v.x, fmaf(v.y, v.y, fmaf(v.z, v.z, fmaf(v.w, v.w, zs))));
        }
        #pragma unroll
        for (int off = 1; off < 16; off <<= 1) zs += __shfl_xor(zs, off);
        if (l15 == 0) {
            idx[row] = bc;
            vq_local += 2.f * bv + zs;               // ||z - e||^2
        }
    }
    block_reduce_add<256>(vq_local, acc + 0);
}

// ---------------- MFMA MLP GEMM: 64 rows x 256 cols, 8 waves ----------------
// MODE_A: 0=bf16 direct, 1=bf16 h + BN(from prologue)+ReLU, 2=gather emb_b, 3=f32 cvt
// MODE_T: 1=f32 T direct, 2=f32 emb gather
template<int MODE_A, int MODE_T, int WRITE_C, int DO_STATS, int DO_LOSS>
__global__ __launch_bounds__(512) void mlp_gemm(
    const void* __restrict__ Asrc, const u16* __restrict__ Wt,
    const float* __restrict__ bias,
    const float* __restrict__ cs_in, const float* __restrict__ cs2_in,
    const float* __restrict__ g_in, const float* __restrict__ beta_in,
    const int* __restrict__ gidx, const float* __restrict__ embf,
    u16* __restrict__ Cb,
    float* __restrict__ colsum, float* __restrict__ colsum2,
    const float* __restrict__ Tf, float* __restrict__ loss_acc)
{
    __shared__ u16 As[64 * 32];
    __shared__ u16 Bs[256 * 32];
    __shared__ float bn_sc[256], bn_sh[256];
    const int t = threadIdx.x;
    const int row0 = blockIdx.x * 64;
    const int lane = t & 63, wave = t >> 6;
    const int wr = wave >> 2, wc = wave & 3;
    const int l15 = lane & 15, lg = lane >> 4;
    const int am = t >> 2, akc = t & 3;

    if (MODE_A == 1) {     // BN finalize prologue (folded bn_finalize_k)
        if (t < 256) {
            float mu  = cs_in[t]  * (1.f / (float)BATCH);
            float var = cs2_in[t] * (1.f / (float)BATCH) - mu * mu;
            float sc = g_in[t] * rsqrtf(var + 1e-5f);
            bn_sc[t] = sc;
            bn_sh[t] = beta_in[t] - mu * sc;
        }
        __syncthreads();
    }

    f32x4 acc[2][4];
    #pragma unroll
    for (int mt = 0; mt < 2; ++mt)
        #pragma unroll
        for (int j = 0; j < 4; ++j)
            acc[mt][j] = (f32x4){0.f, 0.f, 0.f, 0.f};

    for (int k0 = 0; k0 < DD; k0 += 32) {
        if (t < 256) {
            uint4 d;
            if (MODE_A == 3) {
                const float* src = (const float*)Asrc + (size_t)(row0 + am) * DD + k0 + akc * 8;
                float4 f0 = *(const float4*)src;
                float4 f1 = *(const float4*)(src + 4);
                Pack8 pk;
                pk.us[0]=f2b(f0.x); pk.us[1]=f2b(f0.y); pk.us[2]=f2b(f0.z); pk.us[3]=f2b(f0.w);
                pk.us[4]=f2b(f1.x); pk.us[5]=f2b(f1.y); pk.us[6]=f2b(f1.z); pk.us[7]=f2b(f1.w);
                d = pk.v;
            } else if (MODE_A == 2) {
                int code = gidx[row0 + am];
                d = *(const uint4*)((const u16*)Asrc + (size_t)code * DD + k0 + akc * 8);
            } else {
                d = *(const uint4*)((const u16*)Asrc + (size_t)(row0 + am) * DD + k0 + akc * 8);
            }
            if (MODE_A == 1) {
                Pack8 pk; pk.v = d;
                #pragma unroll
                for (int e = 0; e < 8; ++e) {
                    int k = k0 + akc * 8 + e;
                    float v = fmaf(b2f(pk.us[e]), bn_sc[k], bn_sh[k]);
                    pk.us[e] = f2b(v > 0.f ? v : 0.f);
                }
                d = pk.v;
            }
            *(uint4*)(As + ((am * 32 + akc * 8) ^ ((am & 7) << 3))) = d;
        }
        #pragma unroll
        for (int q = 0; q < 2; ++q) {
            int ch = t * 2 + q;
            int bn = ch >> 2, bkc = ch & 3;
            uint4 d = *(const uint4*)(Wt + bn * DD + k0 + bkc * 8);
            *(uint4*)(Bs + ((bn * 32 + bkc * 8) ^ ((bn & 7) << 3))) = d;
        }
        __syncthreads();

        bf16x8 af[2], bfr[4];
        #pragma unroll
        for (int mt = 0; mt < 2; ++mt) {
            int m = wr * 32 + mt * 16 + l15;
            af[mt] = *(const bf16x8*)(As + ((m * 32 + lg * 8) ^ ((m & 7) << 3)));
        }
        #pragma unroll
        for (int j = 0; j < 4; ++j) {
            int n = wc * 64 + j * 16 + l15;
            bfr[j] = *(const bf16x8*)(Bs + ((n * 32 + lg * 8) ^ ((n & 7) << 3)));
        }
        #pragma unroll
        for (int mt = 0; mt < 2; ++mt)
            #pragma unroll
            for (int j = 0; j < 4; ++j)
                acc[mt][j] = __builtin_amdgcn_mfma_f32_16x16x32_bf16(af[mt], bfr[j], acc[mt][j], 0, 0, 0);
        __syncthreads();
    }

    float lsum = 0.f;
    #pragma unroll
    for (int j = 0; j < 4; ++j) {
        int c = wc * 64 + j * 16 + l15;
        float bc = bias[c];
        float cs = 0.f, cs2 = 0.f;
        #pragma unroll
        for (int mt = 0; mt < 2; ++mt) {
            #pragma unroll
            for (int r = 0; r < 4; ++r) {
                int row = row0 + wr * 32 + mt * 16 + lg * 4 + r;
                float y = acc[mt][j][r] + bc;
                if (WRITE_C) Cb[(size_t)row * DD + c] = f2b(y);
                if (DO_STATS) { cs += y; cs2 = fmaf(y, y, cs2); }
                if (DO_LOSS) {
                    float tv = (MODE_T == 2) ? embf[(size_t)gidx[row] * DD + c]
                                             : Tf[(size_t)row * DD + c];
                    float dd = y - tv;
                    lsum = fmaf(dd, dd, lsum);
                }
            }
        }
        if (DO_STATS) {
            cs  += __shfl_xor(cs, 16);  cs  += __shfl_xor(cs, 32);
            cs2 += __shfl_xor(cs2, 16); cs2 += __shfl_xor(cs2, 32);
            if (lg == 0) {
                atomicAdd(&colsum[c], cs);
                atomicAdd(&colsum2[c], cs2);
            }
        }
    }
    if (DO_LOSS) block_reduce_add<512>(lsum, loss_acc);
}

// ---------------- lattice: wave per row, coalesced ----------------
__global__ __launch_bounds__(256) void latt_k(
    const float* __restrict__ emb, const int* __restrict__ idx,
    const float* __restrict__ lattW, const float* __restrict__ lattb,
    const float* __restrict__ smean, const float* __restrict__ sstd,
    const float* __restrict__ lsc, float* acc)
{
    __shared__ float lwT[6][256];
    const int t = threadIdx.x, lane = t & 63, wave = t >> 6;
    for (int o = t; o < 1536; o += 256) {
        int d = o / 6, j = o - d * 6;
        lwT[j][d] = lattW[o];
    }
    __syncthreads();
    float s = 0.f;
    const int b0 = blockIdx.x * 32 + wave * 8;
    for (int rr = 0; rr < 8; ++rr) {
        int b = b0 + rr;
        const float* q = emb + (size_t)idx[b] * DD;
        float a[6] = {0.f,0.f,0.f,0.f,0.f,0.f};
        #pragma unroll
        for (int dd = 0; dd < 4; ++dd) {
            int d = lane + dd * 64;
            float qv = q[d];
            #pragma unroll
            for (int j = 0; j < 6; ++j) a[j] = fmaf(qv, lwT[j][d], a[j]);
        }
        #pragma unroll
        for (int j = 0; j < 6; ++j) {
            #pragma unroll
            for (int off = 1; off < 64; off <<= 1) a[j] += __shfl_xor(a[j], off);
        }
        if (lane == 0) {
            #pragma unroll
            for (int j = 0; j < 6; ++j) {
                float pred = a[j] + lattb[j];
                float tgt = (lsc[(size_t)b * 6 + j] - smean[j]) / sstd[j];
                float dd2 = pred - tgt;
                s = fmaf(dd2, dd2, s);
            }
        }
    }
    block_reduce_add<256>(s, acc + 4);
}

// ---------------- atom: MFMA GEMM 64 x 112 + in-register CE ----------------
__global__ __launch_bounds__(256) void atom_k(
    const float* __restrict__ zn, const u16* __restrict__ Wat, const float* __restrict__ ba,
    const int* __restrict__ atomic_nums, const int* __restrict__ batch_idx,
    float* __restrict__ gsums, float* __restrict__ gcnts)
{
    __shared__ u16 As[64 * 32];
    __shared__ u16 Bs[112 * 32];
    const int t = threadIdx.x;
    const int n0 = blockIdx.x * 64;
    const int lane = t & 63, wave = t >> 6;
    const int l15 = lane & 15, lg = lane >> 4;
    const int am = t >> 2, akc = t & 3;

    f32x4 acc[7];
    #pragma unroll
    for (int j = 0; j < 7; ++j) acc[j] = (f32x4){0.f, 0.f, 0.f, 0.f};

    for (int k0 = 0; k0 < DD; k0 += 32) {
        {
            const float* src = zn + (size_t)(n0 + am) * DD + k0 + akc * 8;
            float4 f0 = *(const float4*)src;
            float4 f1 = *(const float4*)(src + 4);
            Pack8 pk;
            pk.us[0]=f2b(f0.x); pk.us[1]=f2b(f0.y); pk.us[2]=f2b(f0.z); pk.us[3]=f2b(f0.w);
            pk.us[4]=f2b(f1.x); pk.us[5]=f2b(f1.y); pk.us[6]=f2b(f1.z); pk.us[7]=f2b(f1.w);
            *(uint4*)(As + ((am * 32 + akc * 8) ^ ((am & 7) << 3))) = pk.v;
        }
        {
            int bn = t >> 2, bkc = t & 3;
            uint4 d = *(const uint4*)(Wat + bn * DD + k0 + bkc * 8);
            *(uint4*)(Bs + ((bn * 32 + bkc * 8) ^ ((bn & 7) << 3))) = d;
            int ch = t + 256;
            if (ch < 448) {
                int bn2 = ch >> 2, bkc2 = ch & 3;
                uint4 d2 = *(const uint4*)(Wat + bn2 * DD + k0 + bkc2 * 8);
                *(uint4*)(Bs + ((bn2 * 32 + bkc2 * 8) ^ ((bn2 & 7) << 3))) = d2;
            }
        }
        __syncthreads();

        int m = wave * 16 + l15;
        bf16x8 af = *(const bf16x8*)(As + ((m * 32 + lg * 8) ^ ((m & 7) << 3)));
        #pragma unroll
        for (int j = 0; j < 7; ++j) {
            int n = j * 16 + l15;
            bf16x8 bfv = *(const bf16x8*)(Bs + ((n * 32 + lg * 8) ^ ((n & 7) << 3)));
            acc[j] = __builtin_amdgcn_mfma_f32_16x16x32_bf16(af, bfv, acc[j], 0, 0, 0);
        }
        __syncthreads();
    }

    #pragma unroll
    for (int r = 0; r < 4; ++r) {
        float y[7];
        float mx = -3.4e38f;
        #pragma unroll
        for (int j = 0; j < 7; ++j) {
            int c = j * 16 + l15;
            y[j] = (c < KC) ? (acc[j][r] + ba[c]) : -3.4e38f;
            mx = fmaxf(mx, y[j]);
        }
        mx = fmaxf(mx, __shfl_xor(mx, 1));
        mx = fmaxf(mx, __shfl_xor(mx, 2));
        mx = fmaxf(mx, __shfl_xor(mx, 4));
        mx = fmaxf(mx, __shfl_xor(mx, 8));
        float s = 0.f;
        #pragma unroll
        for (int j = 0; j < 7; ++j) {
            int c = j * 16 + l15;
            if (c < KC) s += expf(y[j] - mx);
        }
        s += __shfl_xor(s, 1); s += __shfl_xor(s, 2);
        s += __shfl_xor(s, 4); s += __shfl_xor(s, 8);
        int n = n0 + wave * 16 + lg * 4 + r;
        int tgt = atomic_nums[n];
        float tv = 0.f;
        #pragma unroll
        for (int j = 0; j < 7; ++j)
            tv += (((tgt & 15) == l15) && ((tgt >> 4) == j)) ? y[j] : 0.f;
        tv += __shfl_xor(tv, 1); tv += __shfl_xor(tv, 2);
        tv += __shfl_xor(tv, 4); tv += __shfl_xor(tv, 8);
        if (l15 == 0) {
            float ce = logf(s) + mx - tv;
            int b = batch_idx[n];
            atomicAdd(&gsums[b], ce);
            atomicAdd(&gcnts[b], 1.f);
        }
    }
}

__global__ __launch_bounds__(256) void atom_final_k(const float* __restrict__ gsums,
                                                    const float* __restrict__ gcnts,
                                                    float* acc) {
    int b = blockIdx.x * 256 + threadIdx.x;
    float v = gsums[b] / fmaxf(gcnts[b], 1.f);
    block_reduce_add<256>(v, acc + 5);
}

__global__ void finalize_k(const float* __restrict__ acc, float* __restrict__ out) {
    if (threadIdx.x == 0) {
        const float inv_bd = 1.f / ((float)BATCH * (float)DD);
        float cyc = (acc[1] + acc[2] + acc[3]) * inv_bd;
        float vq = 2.f * acc[0] * inv_bd;
        float latt = acc[4] / ((float)BATCH * 6.f) * 10.f;
        float atom = acc[5] * (1.f / (float)BATCH);
        out[0] = cyc + atom + latt + vq;
        out[1] = cyc;
        out[2] = atom;
        out[3] = latt;
        out[4] = vq;
    }
}

extern "C" void kernel_launch(void* const* d_in, const int* in_sizes, int n_in,
                              void* d_out, int out_size, void* d_ws, size_t ws_size,
                              hipStream_t stream)
{
    const float* z1      = (const float*)d_in[0];
    const float* z2      = (const float*)d_in[1];
    const float* zn      = (const float*)d_in[2];
    const float* emb     = (const float*)d_in[3];
    const float* proj_W1 = (const float*)d_in[4];
    const float* proj_b1 = (const float*)d_in[5];
    const float* proj_g  = (const float*)d_in[6];
    const float* proj_be = (const float*)d_in[7];
    const float* proj_W2 = (const float*)d_in[8];
    const float* proj_b2 = (const float*)d_in[9];
    const float* invp_W1 = (const float*)d_in[10];
    const float* invp_b1 = (const float*)d_in[11];
    const float* invp_g  = (const float*)d_in[12];
    const float* invp_be = (const float*)d_in[13];
    const float* invp_W2 = (const float*)d_in[14];
    const float* invp_b2 = (const float*)d_in[15];
    const float* latt_W  = (const float*)d_in[16];
    const float* latt_b  = (const float*)d_in[17];
    const float* atom_W  = (const float*)d_in[18];
    const float* atom_b  = (const float*)d_in[19];
    const float* smean   = (const float*)d_in[20];
    const float* sstd    = (const float*)d_in[21];
    const float* lsc     = (const float*)d_in[22];
    const int* batch_idx   = (const int*)d_in[24];
    const int* atomic_nums = (const int*)d_in[25];
    float* out = (float*)d_out;
    float* ws  = (float*)d_ws;

    float* acc     = ws + 0;
    float* colsum  = ws + 16;
    float* colsum2 = ws + 784;
    float* gsums   = ws + 1552;
    float* gcnts   = ws + 34320;
    float* enorm   = ws + 67088;
    int*   idx     = (int*)(ws + 67216);
    u16* wt_proj1  = (u16*)(ws + 100000);
    u16* wt_proj2  = (u16*)(ws + 132768);
    u16* wt_invp1  = (u16*)(ws + 165536);
    u16* wt_invp2  = (u16*)(ws + 198304);
    u16* wat       = (u16*)(ws + 231072);
    u16* embT_hi   = (u16*)(ws + 245408);
    u16* embT_lo   = (u16*)(ws + 259744);
    u16* emb_b     = (u16*)(ws + 274080);
    u16* h_b       = (u16*)(ws + 286880);
    u16* p1_b      = (u16*)(ws + 4481184);

    hipMemsetAsync(d_ws, 0, 67088 * sizeof(float), stream);

    // setup
    transpose_cvt256_k<<<256, 256, 0, stream>>>(proj_W1, wt_proj1);
    transpose_cvt256_k<<<256, 256, 0, stream>>>(proj_W2, wt_proj2);
    transpose_cvt256_k<<<256, 256, 0, stream>>>(invp_W1, wt_invp1);
    transpose_cvt256_k<<<256, 256, 0, stream>>>(invp_W2, wt_invp2);
    transpose_cvt_atom_k<<<112, 256, 0, stream>>>(atom_W, wat);
    embT_k<<<112, 256, 0, stream>>>(emb, embT_hi, embT_lo);
    cvt_bf16_k<<<13, 256, 0, stream>>>(emb, emb_b, KC * DD / 8);
    enorm_k<<<KC, 64, 0, stream>>>(emb, enorm);

    // VQ (argmin + vq_loss fused)
    vq_k<<<512, 256, 0, stream>>>(z2, embT_hi, embT_lo, enorm, idx, acc);

    // MLP1: p1 = mlp_bn(z1, proj), loss_p vs quant
    mlp_gemm<3,1,1,1,0><<<512, 512, 0, stream>>>(z1, wt_proj1, proj_b1,
        nullptr, nullptr, nullptr, nullptr, idx, emb, h_b, colsum+0, colsum2+0, nullptr, nullptr);
    mlp_gemm<1,2,1,0,1><<<512, 512, 0, stream>>>(h_b, wt_proj2, proj_b2,
        colsum+0, colsum2+0, proj_g, proj_be, idx, emb, p1_b, nullptr, nullptr, nullptr, acc+1);
    // MLP2: mlp_bn(quant, invp), loss_i vs z1
    mlp_gemm<2,1,1,1,0><<<512, 512, 0, stream>>>(emb_b, wt_invp1, invp_b1,
        nullptr, nullptr, nullptr, nullptr, idx, emb, h_b, colsum+256, colsum2+256, nullptr, nullptr);
    mlp_gemm<1,1,0,0,1><<<512, 512, 0, stream>>>(h_b, wt_invp2, invp_b2,
        colsum+256, colsum2+256, invp_g, invp_be, idx, emb, nullptr, nullptr, nullptr, z1, acc+2);
    // MLP3: mlp_bn(p1, invp), loss_c vs z1
    mlp_gemm<0,1,1,1,0><<<512, 512, 0, stream>>>(p1_b, wt_invp1, invp_b1,
        nullptr, nullptr, nullptr, nullptr, idx, emb, h_b, colsum+512, colsum2+512, nullptr, nullptr);
    mlp_gemm<1,1,0,0,1><<<512, 512, 0, stream>>>(h_b, wt_invp2, invp_b2,
        colsum+512, colsum2+512, invp_g, invp_be, idx, emb, nullptr, nullptr, nullptr, z1, acc+3);

    latt_k<<<1024, 256, 0, stream>>>(emb, idx, latt_W, latt_b, smean, sstd, lsc, acc);
    atom_k<<<4096, 256, 0, stream>>>(zn, wat, atom_b, atomic_nums, batch_idx, gsums, gcnts);
    atom_final_k<<<128, 256, 0, stream>>>(gsums, gcnts, acc);
    finalize_k<<<1, 64, 0, stream>>>(acc, out);
}

// Round 9
// 718.816 us; speedup vs baseline: 1.2746x; 1.0177x over previous
//
#include <hip/hip_runtime.h>
#include <math.h>

#define BATCH 32768
#define DD 256
#define KC 100
#define NATOMS 262144

typedef unsigned short u16;
typedef __attribute__((ext_vector_type(8))) short bf16x8;
typedef __attribute__((ext_vector_type(4))) float f32x4;

union Pack8 { uint4 v; u16 us[8]; };

__device__ inline u16 f2b(float f) {
    unsigned u = __float_as_uint(f);
    unsigned r = (u + 0x7fffu + ((u >> 16) & 1u)) >> 16;
    return (u16)r;
}
__device__ inline float b2f(u16 x) { return __uint_as_float(((unsigned)x) << 16); }
__device__ inline unsigned cvtpk(float lo, float hi) {
    unsigned r;
    asm("v_cvt_pk_bf16_f32 %0, %1, %2" : "=v"(r) : "v"(lo), "v"(hi));
    return r;
}
__device__ inline uint4 pack8(float4 a, float4 b) {
    uint4 r;
    r.x = cvtpk(a.x, a.y); r.y = cvtpk(a.z, a.w);
    r.z = cvtpk(b.x, b.y); r.w = cvtpk(b.z, b.w);
    return r;
}

// ---------------- ws layout (float offsets) ----------------
// acc[16]@0 colsum[768]@16 colsum2[768]@784 gsums[32768]@1552 gcnts[32768]@34320
//   (zero first 67088 floats)
// enorm[128]@67088 idx int[32768]@67216
// wt_proj1@100000 wt_proj2@132768 wt_invp1@165536 wt_invp2@198304 (32768 fl each)
// wat@231072 (14336 fl) embT_hi@245408 embT_lo@259744 (14336 fl each)
// emb_b@274080 (12800 fl) h_b@286880 p1_b@4481184 (4194304 fl each) -> ~34.7MB

template<int NT>
__device__ inline void block_reduce_add(float v, float* target) {
    __shared__ float red[NT];
    red[threadIdx.x] = v;
    __syncthreads();
    for (int s = NT/2; s > 0; s >>= 1) {
        if ((int)threadIdx.x < s) red[threadIdx.x] += red[threadIdx.x + s];
        __syncthreads();
    }
    if (threadIdx.x == 0) atomicAdd(target, red[0]);
}

// ---------------- merged setup: transposes + embT + emb cvt + enorm ----------------
__global__ __launch_bounds__(256) void setup_k(
    const float* __restrict__ pW1, const float* __restrict__ pW2,
    const float* __restrict__ iW1, const float* __restrict__ iW2,
    const float* __restrict__ aW, const float* __restrict__ emb,
    u16* __restrict__ wtp1, u16* __restrict__ wtp2,
    u16* __restrict__ wti1, u16* __restrict__ wti2,
    u16* __restrict__ wat, u16* __restrict__ eh, u16* __restrict__ el,
    u16* __restrict__ embb, float* __restrict__ enorm)
{
    const int blk = blockIdx.x, t = threadIdx.x;
    if (blk < 1024) {                       // 4x 256x256 transpose+cvt
        int g = blk >> 8;
        const float* W = (g == 0) ? pW1 : (g == 1) ? pW2 : (g == 2) ? iW1 : iW2;
        u16* Wt = (g == 0) ? wtp1 : (g == 1) ? wtp2 : (g == 2) ? wti1 : wti2;
        int o = (blk & 255) * 256 + t;
        int n = o >> 8, k = o & 255;
        Wt[o] = f2b(W[k * 256 + n]);
    } else if (blk < 1136) {                // atom_W transpose (112x256)
        int o = (blk - 1024) * 256 + t;
        int n = o >> 8, k = o & 255;
        wat[o] = (n < KC) ? f2b(aW[k * KC + n]) : (u16)0;
    } else if (blk < 1248) {                // emb hi/lo split (112x256)
        int o = (blk - 1136) * 256 + t;
        int n = o >> 8, d = o & 255;
        float v = (n < KC) ? emb[n * DD + d] : 0.f;
        u16 h = f2b(v);
        eh[o] = h;
        el[o] = f2b(v - b2f(h));
    } else if (blk < 1255) {                // emb -> bf16 (1600 x 8 elems)
        int i = (blk - 1248) * 256 + t;
        if (i < 1600) {
            const float4* p = (const float4*)(emb + (size_t)i * 8);
            *(uint4*)(embb + (size_t)i * 8) = pack8(p[0], p[1]);
        }
    } else {                                // enorm: wave per code row
        int row = (blk - 1255) * 4 + (t >> 6);
        int lane = t & 63;
        if (row < KC) {
            float4 v = *(const float4*)(emb + (size_t)row * DD + lane * 4);
            float s = v.x*v.x + v.y*v.y + v.z*v.z + v.w*v.w;
            #pragma unroll
            for (int off = 1; off < 64; off <<= 1) s += __shfl_xor(s, off);
            if (lane == 0) enorm[row] = 0.5f * s;
        }
    }
}

// ---------------- VQ: MFMA hi/lo distance + fused argmin + vq_loss + ||z||^2 ----------------
__global__ __launch_bounds__(256) void vq_k(
    const float* __restrict__ z2, const u16* __restrict__ Eh, const u16* __restrict__ El,
    const float* __restrict__ enorm, int* __restrict__ idx, float* acc)
{
    __shared__ u16 Ah[64*32], Al[64*32], Bh[112*32], Bl[112*32];
    __shared__ float zrow[64];
    const int t = threadIdx.x;
    const int n0 = blockIdx.x * 64;
    const int lane = t & 63, wave = t >> 6;
    const int l15 = lane & 15, lg = lane >> 4;
    const int am = t >> 2, akc = t & 3;

    f32x4 dot[7];
    #pragma unroll
    for (int j = 0; j < 7; ++j) dot[j] = (f32x4){0.f, 0.f, 0.f, 0.f};
    float zsq = 0.f;

    for (int k0 = 0; k0 < DD; k0 += 32) {
        {   // A stage: f32 -> hi/lo bf16, accumulate z^2
            const float* src = z2 + (size_t)(n0 + am) * DD + k0 + akc * 8;
            float4 f0 = *(const float4*)src;
            float4 f1 = *(const float4*)(src + 4);
            zsq += f0.x*f0.x + f0.y*f0.y + f0.z*f0.z + f0.w*f0.w
                 + f1.x*f1.x + f1.y*f1.y + f1.z*f1.z + f1.w*f1.w;
            uint4 hv = pack8(f0, f1);
            Pack8 ph; ph.v = hv;
            float4 l0 = make_float4(f0.x - b2f(ph.us[0]), f0.y - b2f(ph.us[1]),
                                    f0.z - b2f(ph.us[2]), f0.w - b2f(ph.us[3]));
            float4 l1 = make_float4(f1.x - b2f(ph.us[4]), f1.y - b2f(ph.us[5]),
                                    f1.z - b2f(ph.us[6]), f1.w - b2f(ph.us[7]));
            int off = (am * 32 + akc * 8) ^ ((am & 7) << 3);
            *(uint4*)(Ah + off) = hv;
            *(uint4*)(Al + off) = pack8(l0, l1);
        }
        {   // B stage: 448 chunks each for hi/lo
            int bn = t >> 2, bkc = t & 3;
            int off = (bn * 32 + bkc * 8) ^ ((bn & 7) << 3);
            *(uint4*)(Bh + off) = *(const uint4*)(Eh + bn * DD + k0 + bkc * 8);
            *(uint4*)(Bl + off) = *(const uint4*)(El + bn * DD + k0 + bkc * 8);
            int c2 = t + 256;
            if (c2 < 448) {
                int bn2 = c2 >> 2, bkc2 = c2 & 3;
                int off2 = (bn2 * 32 + bkc2 * 8) ^ ((bn2 & 7) << 3);
                *(uint4*)(Bh + off2) = *(const uint4*)(Eh + bn2 * DD + k0 + bkc2 * 8);
                *(uint4*)(Bl + off2) = *(const uint4*)(El + bn2 * DD + k0 + bkc2 * 8);
            }
        }
        __syncthreads();

        int m = wave * 16 + l15;
        int aoff = (m * 32 + lg * 8) ^ ((m & 7) << 3);
        bf16x8 ah = *(const bf16x8*)(Ah + aoff);
        bf16x8 al = *(const bf16x8*)(Al + aoff);
        #pragma unroll
        for (int j = 0; j < 7; ++j) {
            int n = j * 16 + l15;
            int boff = (n * 32 + lg * 8) ^ ((n & 7) << 3);
            bf16x8 bh = *(const bf16x8*)(Bh + boff);
            bf16x8 bl = *(const bf16x8*)(Bl + boff);
            dot[j] = __builtin_amdgcn_mfma_f32_16x16x32_bf16(ah, bh, dot[j], 0, 0, 0);
            dot[j] = __builtin_amdgcn_mfma_f32_16x16x32_bf16(ah, bl, dot[j], 0, 0, 0);
            dot[j] = __builtin_amdgcn_mfma_f32_16x16x32_bf16(al, bh, dot[j], 0, 0, 0);
        }
        __syncthreads();
    }

    // ||z||^2 per row: 4 staging threads per row (adjacent lanes)
    zsq += __shfl_xor(zsq, 1);
    zsq += __shfl_xor(zsq, 2);
    if ((t & 3) == 0) zrow[am] = zsq;
    __syncthreads();

    // argmin + vq accumulation. row = n0 + wave*16 + lg*4 + r, col = j*16+l15
    float vq_local = 0.f;
    #pragma unroll
    for (int r = 0; r < 4; ++r) {
        int row = n0 + wave * 16 + lg * 4 + r;
        float bv = 3.4e38f; int bc = 1000;
        #pragma unroll
        for (int j = 0; j < 7; ++j) {
            int c = j * 16 + l15;
            if (c < KC) {
                float y = enorm[c] - dot[j][r];      // 0.5||e||^2 - z.e
                if (y < bv) { bv = y; bc = c; }
            }
        }
        #pragma unroll
        for (int off = 1; off < 16; off <<= 1) {
            float ov = __shfl_xor(bv, off);
            int   oc = __shfl_xor(bc, off);
            if (ov < bv || (ov == bv && oc < bc)) { bv = ov; bc = oc; }
        }
        if (l15 == 0) {
            idx[row] = bc;
            vq_local += 2.f * bv + zrow[row - n0];   // ||z - e||^2
        }
    }
    block_reduce_add<256>(vq_local, acc + 0);
}

// ---------------- MFMA MLP GEMM: 128 rows x 128 cols, 8 waves (4m x 2n) ----------------
// MODE_A: 0=bf16 direct, 1=bf16 h + BN(prologue)+ReLU, 2=gather emb_b, 3=f32 cvt
// MODE_T: 1=f32 T direct, 2=f32 emb gather
template<int MODE_A, int MODE_T, int WRITE_C, int DO_STATS, int DO_LOSS>
__global__ __launch_bounds__(512) void mlp_gemm(
    const void* __restrict__ Asrc, const u16* __restrict__ Wt,
    const float* __restrict__ bias,
    const float* __restrict__ cs_in, const float* __restrict__ cs2_in,
    const float* __restrict__ g_in, const float* __restrict__ beta_in,
    const int* __restrict__ gidx, const float* __restrict__ embf,
    u16* __restrict__ Cb,
    float* __restrict__ colsum, float* __restrict__ colsum2,
    const float* __restrict__ Tf, float* __restrict__ loss_acc)
{
    __shared__ u16 As[128 * 32];
    __shared__ u16 Bs[128 * 32];
    __shared__ float bn_sc[256], bn_sh[256];
    const int t = threadIdx.x;
    const int bid = blockIdx.x;
    const int row0 = (bid >> 1) * 128;
    const int col0 = (bid & 1) * 128;
    const int lane = t & 63, wave = t >> 6;
    const int wm = wave >> 1, wn = wave & 1;   // 4 x 2 wave grid
    const int l15 = lane & 15, lg = lane >> 4;
    const int sr = t >> 2, skc = t & 3;        // staging row/col 0..127, k-chunk

    if (MODE_A == 1) {     // folded BN finalize
        if (t < 256) {
            float mu  = cs_in[t]  * (1.f / (float)BATCH);
            float var = cs2_in[t] * (1.f / (float)BATCH) - mu * mu;
            float sc = g_in[t] * rsqrtf(var + 1e-5f);
            bn_sc[t] = sc;
            bn_sh[t] = beta_in[t] - mu * sc;
        }
        __syncthreads();
    }

    f32x4 acc[2][4];
    #pragma unroll
    for (int mt = 0; mt < 2; ++mt)
        #pragma unroll
        for (int j = 0; j < 4; ++j)
            acc[mt][j] = (f32x4){0.f, 0.f, 0.f, 0.f};

    for (int k0 = 0; k0 < DD; k0 += 32) {
        {   // A chunk (every thread)
            uint4 d;
            if (MODE_A == 3) {
                const float* src = (const float*)Asrc + (size_t)(row0 + sr) * DD + k0 + skc * 8;
                d = pack8(*(const float4*)src, *(const float4*)(src + 4));
            } else if (MODE_A == 2) {
                int code = gidx[row0 + sr];
                d = *(const uint4*)((const u16*)Asrc + (size_t)code * DD + k0 + skc * 8);
            } else {
                d = *(const uint4*)((const u16*)Asrc + (size_t)(row0 + sr) * DD + k0 + skc * 8);
            }
            if (MODE_A == 1) {
                Pack8 pk; pk.v = d;
                float f[8];
                #pragma unroll
                for (int e = 0; e < 8; ++e) {
                    int k = k0 + skc * 8 + e;
                    float v = fmaf(b2f(pk.us[e]), bn_sc[k], bn_sh[k]);
                    f[e] = v > 0.f ? v : 0.f;
                }
                d = pack8(make_float4(f[0], f[1], f[2], f[3]),
                          make_float4(f[4], f[5], f[6], f[7]));
            }
            *(uint4*)(As + ((sr * 32 + skc * 8) ^ ((sr & 7) << 3))) = d;
        }
        {   // B chunk (every thread)
            uint4 d = *(const uint4*)(Wt + (size_t)(col0 + sr) * DD + k0 + skc * 8);
            *(uint4*)(Bs + ((sr * 32 + skc * 8) ^ ((sr & 7) << 3))) = d;
        }
        __syncthreads();

        bf16x8 af[2], bfr[4];
        #pragma unroll
        for (int mt = 0; mt < 2; ++mt) {
            int m = wm * 32 + mt * 16 + l15;
            af[mt] = *(const bf16x8*)(As + ((m * 32 + lg * 8) ^ ((m & 7) << 3)));
        }
        #pragma unroll
        for (int j = 0; j < 4; ++j) {
            int n = wn * 64 + j * 16 + l15;
            bfr[j] = *(const bf16x8*)(Bs + ((n * 32 + lg * 8) ^ ((n & 7) << 3)));
        }
        #pragma unroll
        for (int mt = 0; mt < 2; ++mt)
            #pragma unroll
            for (int j = 0; j < 4; ++j)
                acc[mt][j] = __builtin_amdgcn_mfma_f32_16x16x32_bf16(af[mt], bfr[j], acc[mt][j], 0, 0, 0);
        __syncthreads();
    }

    float lsum = 0.f;
    #pragma unroll
    for (int j = 0; j < 4; ++j) {
        int c = col0 + wn * 64 + j * 16 + l15;
        float bc = bias[c];
        float cs = 0.f, cs2 = 0.f;
        #pragma unroll
        for (int mt = 0; mt < 2; ++mt) {
            #pragma unroll
            for (int r = 0; r < 4; ++r) {
                int row = row0 + wm * 32 + mt * 16 + lg * 4 + r;
                float y = acc[mt][j][r] + bc;
                if (WRITE_C) Cb[(size_t)row * DD + c] = f2b(y);
                if (DO_STATS) { cs += y; cs2 = fmaf(y, y, cs2); }
                if (DO_LOSS) {
                    float tv = (MODE_T == 2) ? embf[(size_t)gidx[row] * DD + c]
                                             : Tf[(size_t)row * DD + c];
                    float dd = y - tv;
                    lsum = fmaf(dd, dd, lsum);
                }
            }
        }
        if (DO_STATS) {
            cs  += __shfl_xor(cs, 16);  cs  += __shfl_xor(cs, 32);
            cs2 += __shfl_xor(cs2, 16); cs2 += __shfl_xor(cs2, 32);
            if (lg == 0) {
                atomicAdd(&colsum[c], cs);
                atomicAdd(&colsum2[c], cs2);
            }
        }
    }
    if (DO_LOSS) block_reduce_add<512>(lsum, loss_acc);
}

// ---------------- lattice: wave per row, coalesced ----------------
__global__ __launch_bounds__(256) void latt_k(
    const float* __restrict__ emb, const int* __restrict__ idx,
    const float* __restrict__ lattW, const float* __restrict__ lattb,
    const float* __restrict__ smean, const float* __restrict__ sstd,
    const float* __restrict__ lsc, float* acc)
{
    __shared__ float lwT[6][256];
    const int t = threadIdx.x, lane = t & 63, wave = t >> 6;
    for (int o = t; o < 1536; o += 256) {
        int d = o / 6, j = o - d * 6;
        lwT[j][d] = lattW[o];
    }
    __syncthreads();
    float s = 0.f;
    const int b0 = blockIdx.x * 32 + wave * 8;
    for (int rr = 0; rr < 8; ++rr) {
        int b = b0 + rr;
        const float* q = emb + (size_t)idx[b] * DD;
        float a[6] = {0.f,0.f,0.f,0.f,0.f,0.f};
        #pragma unroll
        for (int dd = 0; dd < 4; ++dd) {
            int d = lane + dd * 64;
            float qv = q[d];
            #pragma unroll
            for (int j = 0; j < 6; ++j) a[j] = fmaf(qv, lwT[j][d], a[j]);
        }
        #pragma unroll
        for (int j = 0; j < 6; ++j) {
            #pragma unroll
            for (int off = 1; off < 64; off <<= 1) a[j] += __shfl_xor(a[j], off);
        }
        if (lane == 0) {
            #pragma unroll
            for (int j = 0; j < 6; ++j) {
                float pred = a[j] + lattb[j];
                float tgt = (lsc[(size_t)b * 6 + j] - smean[j]) / sstd[j];
                float dd2 = pred - tgt;
                s = fmaf(dd2, dd2, s);
            }
        }
    }
    block_reduce_add<256>(s, acc + 4);
}

// ---------------- atom: MFMA GEMM 64 x 112 + in-register CE ----------------
__global__ __launch_bounds__(256) void atom_k(
    const float* __restrict__ zn, const u16* __restrict__ Wat, const float* __restrict__ ba,
    const int* __restrict__ atomic_nums, const int* __restrict__ batch_idx,
    float* __restrict__ gsums, float* __restrict__ gcnts)
{
    __shared__ u16 As[64 * 32];
    __shared__ u16 Bs[112 * 32];
    const int t = threadIdx.x;
    const int n0 = blockIdx.x * 64;
    const int lane = t & 63, wave = t >> 6;
    const int l15 = lane & 15, lg = lane >> 4;
    const int am = t >> 2, akc = t & 3;

    f32x4 acc[7];
    #pragma unroll
    for (int j = 0; j < 7; ++j) acc[j] = (f32x4){0.f, 0.f, 0.f, 0.f};

    for (int k0 = 0; k0 < DD; k0 += 32) {
        {
            const float* src = zn + (size_t)(n0 + am) * DD + k0 + akc * 8;
            uint4 d = pack8(*(const float4*)src, *(const float4*)(src + 4));
            *(uint4*)(As + ((am * 32 + akc * 8) ^ ((am & 7) << 3))) = d;
        }
        {
            int bn = t >> 2, bkc = t & 3;
            uint4 d = *(const uint4*)(Wat + bn * DD + k0 + bkc * 8);
            *(uint4*)(Bs + ((bn * 32 + bkc * 8) ^ ((bn & 7) << 3))) = d;
            int ch = t + 256;
            if (ch < 448) {
                int bn2 = ch >> 2, bkc2 = ch & 3;
                uint4 d2 = *(const uint4*)(Wat + bn2 * DD + k0 + bkc2 * 8);
                *(uint4*)(Bs + ((bn2 * 32 + bkc2 * 8) ^ ((bn2 & 7) << 3))) = d2;
            }
        }
        __syncthreads();

        int m = wave * 16 + l15;
        bf16x8 af = *(const bf16x8*)(As + ((m * 32 + lg * 8) ^ ((m & 7) << 3)));
        #pragma unroll
        for (int j = 0; j < 7; ++j) {
            int n = j * 16 + l15;
            bf16x8 bfv = *(const bf16x8*)(Bs + ((n * 32 + lg * 8) ^ ((n & 7) << 3)));
            acc[j] = __builtin_amdgcn_mfma_f32_16x16x32_bf16(af, bfv, acc[j], 0, 0, 0);
        }
        __syncthreads();
    }

    #pragma unroll
    for (int r = 0; r < 4; ++r) {
        float y[7];
        float mx = -3.4e38f;
        #pragma unroll
        for (int j = 0; j < 7; ++j) {
            int c = j * 16 + l15;
            y[j] = (c < KC) ? (acc[j][r] + ba[c]) : -3.4e38f;
            mx = fmaxf(mx, y[j]);
        }
        mx = fmaxf(mx, __shfl_xor(mx, 1));
        mx = fmaxf(mx, __shfl_xor(mx, 2));
        mx = fmaxf(mx, __shfl_xor(mx, 4));
        mx = fmaxf(mx, __shfl_xor(mx, 8));
        float s = 0.f;
        #pragma unroll
        for (int j = 0; j < 7; ++j) {
            int c = j * 16 + l15;
            if (c < KC) s += expf(y[j] - mx);
        }
        s += __shfl_xor(s, 1); s += __shfl_xor(s, 2);
        s += __shfl_xor(s, 4); s += __shfl_xor(s, 8);
        int n = n0 + wave * 16 + lg * 4 + r;
        int tgt = atomic_nums[n];
        float tv = 0.f;
        #pragma unroll
        for (int j = 0; j < 7; ++j)
            tv += (((tgt & 15) == l15) && ((tgt >> 4) == j)) ? y[j] : 0.f;
        tv += __shfl_xor(tv, 1); tv += __shfl_xor(tv, 2);
        tv += __shfl_xor(tv, 4); tv += __shfl_xor(tv, 8);
        if (l15 == 0) {
            float ce = logf(s) + mx - tv;
            int b = batch_idx[n];
            atomicAdd(&gsums[b], ce);
            atomicAdd(&gcnts[b], 1.f);
        }
    }
}

__global__ __launch_bounds__(256) void atom_final_k(const float* __restrict__ gsums,
                                                    const float* __restrict__ gcnts,
                                                    float* acc) {
    int b = blockIdx.x * 256 + threadIdx.x;
    float v = gsums[b] / fmaxf(gcnts[b], 1.f);
    block_reduce_add<256>(v, acc + 5);
}

__global__ void finalize_k(const float* __restrict__ acc, float* __restrict__ out) {
    if (threadIdx.x == 0) {
        const float inv_bd = 1.f / ((float)BATCH * (float)DD);
        float cyc = (acc[1] + acc[2] + acc[3]) * inv_bd;
        float vq = 2.f * acc[0] * inv_bd;
        float latt = acc[4] / ((float)BATCH * 6.f) * 10.f;
        float atom = acc[5] * (1.f / (float)BATCH);
        out[0] = cyc + atom + latt + vq;
        out[1] = cyc;
        out[2] = atom;
        out[3] = latt;
        out[4] = vq;
    }
}

extern "C" void kernel_launch(void* const* d_in, const int* in_sizes, int n_in,
                              void* d_out, int out_size, void* d_ws, size_t ws_size,
                              hipStream_t stream)
{
    const float* z1      = (const float*)d_in[0];
    const float* z2      = (const float*)d_in[1];
    const float* zn      = (const float*)d_in[2];
    const float* emb     = (const float*)d_in[3];
    const float* proj_W1 = (const float*)d_in[4];
    const float* proj_b1 = (const float*)d_in[5];
    const float* proj_g  = (const float*)d_in[6];
    const float* proj_be = (const float*)d_in[7];
    const float* proj_W2 = (const float*)d_in[8];
    const float* proj_b2 = (const float*)d_in[9];
    const float* invp_W1 = (const float*)d_in[10];
    const float* invp_b1 = (const float*)d_in[11];
    const float* invp_g  = (const float*)d_in[12];
    const float* invp_be = (const float*)d_in[13];
    const float* invp_W2 = (const float*)d_in[14];
    const float* invp_b2 = (const float*)d_in[15];
    const float* latt_W  = (const float*)d_in[16];
    const float* latt_b  = (const float*)d_in[17];
    const float* atom_W  = (const float*)d_in[18];
    const float* atom_b  = (const float*)d_in[19];
    const float* smean   = (const float*)d_in[20];
    const float* sstd    = (const float*)d_in[21];
    const float* lsc     = (const float*)d_in[22];
    const int* batch_idx   = (const int*)d_in[24];
    const int* atomic_nums = (const int*)d_in[25];
    float* out = (float*)d_out;
    float* ws  = (float*)d_ws;

    float* acc     = ws + 0;
    float* colsum  = ws + 16;
    float* colsum2 = ws + 784;
    float* gsums   = ws + 1552;
    float* gcnts   = ws + 34320;
    float* enorm   = ws + 67088;
    int*   idx     = (int*)(ws + 67216);
    u16* wt_proj1  = (u16*)(ws + 100000);
    u16* wt_proj2  = (u16*)(ws + 132768);
    u16* wt_invp1  = (u16*)(ws + 165536);
    u16* wt_invp2  = (u16*)(ws + 198304);
    u16* wat       = (u16*)(ws + 231072);
    u16* embT_hi   = (u16*)(ws + 245408);
    u16* embT_lo   = (u16*)(ws + 259744);
    u16* emb_b     = (u16*)(ws + 274080);
    u16* h_b       = (u16*)(ws + 286880);
    u16* p1_b      = (u16*)(ws + 4481184);

    hipMemsetAsync(d_ws, 0, 67088 * sizeof(float), stream);

    setup_k<<<1280, 256, 0, stream>>>(proj_W1, proj_W2, invp_W1, invp_W2, atom_W, emb,
        wt_proj1, wt_proj2, wt_invp1, wt_invp2, wat, embT_hi, embT_lo, emb_b, enorm);

    // VQ (argmin + vq_loss fused)
    vq_k<<<512, 256, 0, stream>>>(z2, embT_hi, embT_lo, enorm, idx, acc);

    // MLP1: p1 = mlp_bn(z1, proj), loss_p vs quant
    mlp_gemm<3,1,1,1,0><<<512, 512, 0, stream>>>(z1, wt_proj1, proj_b1,
        nullptr, nullptr, nullptr, nullptr, idx, emb, h_b, colsum+0, colsum2+0, nullptr, nullptr);
    mlp_gemm<1,2,1,0,1><<<512, 512, 0, stream>>>(h_b, wt_proj2, proj_b2,
        colsum+0, colsum2+0, proj_g, proj_be, idx, emb, p1_b, nullptr, nullptr, nullptr, acc+1);
    // MLP2: mlp_bn(quant, invp), loss_i vs z1
    mlp_gemm<2,1,1,1,0><<<512, 512, 0, stream>>>(emb_b, wt_invp1, invp_b1,
        nullptr, nullptr, nullptr, nullptr, idx, emb, h_b, colsum+256, colsum2+256, nullptr, nullptr);
    mlp_gemm<1,1,0,0,1><<<512, 512, 0, stream>>>(h_b, wt_invp2, invp_b2,
        colsum+256, colsum2+256, invp_g, invp_be, idx, emb, nullptr, nullptr, nullptr, z1, acc+2);
    // MLP3: mlp_bn(p1, invp), loss_c vs z1
    mlp_gemm<0,1,1,1,0><<<512, 512, 0, stream>>>(p1_b, wt_invp1, invp_b1,
        nullptr, nullptr, nullptr, nullptr, idx, emb, h_b, colsum+512, colsum2+512, nullptr, nullptr);
    mlp_gemm<1,1,0,0,1><<<512, 512, 0, stream>>>(h_b, wt_invp2, invp_b2,
        colsum+512, colsum2+512, invp_g, invp_be, idx, emb, nullptr, nullptr, nullptr, z1, acc+3);

    latt_k<<<1024, 256, 0, stream>>>(emb, idx, latt_W, latt_b, smean, sstd, lsc, acc);
    atom_k<<<4096, 256, 0, stream>>>(zn, wat, atom_b, atomic_nums, batch_idx, gsums, gcnts);
    atom_final_k<<<128, 256, 0, stream>>>(gsums, gcnts, acc);
    finalize_k<<<1, 64, 0, stream>>>(acc, out);
}